// Round 9
// baseline (338.761 us; speedup 1.0000x reference)
//
#include <hip/hip_runtime.h>
#include <cstdint>
#include <cstddef>

#define BB 2048
#define LL 96
#define PP 96
#define NN 64
#define HSTRIDE 68   // u32 row stride for packed LDS tiles (64 + 4 pad, 16B-aligned)
#define RSTR 81      // fp32 row stride for k_post result buffer (odd -> bank-spread)

typedef __attribute__((ext_vector_type(8))) short short8;  // 8 bf16 (4 VGPRs)
typedef __attribute__((ext_vector_type(4))) float f32x4;

union U4S8 { uint4 u; short8 s; };

__device__ __forceinline__ float siluf(float x) {
  return x * __builtin_amdgcn_rcpf(1.0f + __expf(-x));
}
__device__ __forceinline__ float tanhf_fast(float x) {
  return 1.0f - 2.0f * __builtin_amdgcn_rcpf(1.0f + __expf(2.0f * x));
}
__device__ __forceinline__ float rlane(float x, int l) {
  return __int_as_float(__builtin_amdgcn_readlane(__float_as_int(x), l));
}

// ---- DPP cross-lane adds (VALU pipe); HW-verified R7/R8 ----
template <int CTRL>
__device__ __forceinline__ float dppadd(float x) {
  int y = __builtin_amdgcn_update_dpp(0, __float_as_int(x), CTRL, 0xF, 0xF, false);
  return x + __int_as_float(y);
}
__device__ __forceinline__ float wave_sum(float x) {
  x = dppadd<0xB1>(x);
  x = dppadd<0x4E>(x);
  x = dppadd<0x141>(x);
  x = dppadd<0x128>(x);
  x += __shfl_xor(x, 16, 64);
  x += __shfl_xor(x, 32, 64);
  return x;
}

// split fp32 -> (bf16 hi | bf16 lo) packed in one u32 (hi in top 16).
__device__ __forceinline__ uint32_t packsplit(float f) {
  uint32_t b = __float_as_uint(f);
  uint32_t h = b & 0xFFFF0000u;
  float r = f - __uint_as_float(h);
  return h | (__float_as_uint(r) >> 16);
}
// reconstruct fp32 from packed (exact hi+lo sum)
__device__ __forceinline__ float unpackf(uint32_t p) {
  return __uint_as_float(p & 0xFFFF0000u) + __uint_as_float(p << 16);
}
__device__ __forceinline__ void splitpack2(float f0, float f1, uint32_t& dhi, uint32_t& dlo) {
  uint32_t b0 = __float_as_uint(f0), b1 = __float_as_uint(f1);
  uint32_t h0 = b0 & 0xFFFF0000u, h1 = b1 & 0xFFFF0000u;
  float r0 = f0 - __uint_as_float(h0), r1 = f1 - __uint_as_float(h1);
  dhi = (h0 >> 16) | h1;
  dlo = (__float_as_uint(r0) >> 16) | (__float_as_uint(r1) & 0xFFFF0000u);
}
__device__ __forceinline__ void unpack2(uint32_t p0, uint32_t p1, uint32_t& dhi, uint32_t& dlo) {
  dhi = (p0 >> 16) | (p1 & 0xFFFF0000u);
  dlo = (p0 & 0xFFFFu) | (p1 << 16);
}
__device__ __forceinline__ void readfrag(const uint32_t* p, short8& hi, short8& lo) {
  uint4 pa = *(const uint4*)p;
  uint4 pb = *(const uint4*)(p + 4);
  U4S8 h, l;
  unpack2(pa.x, pa.y, h.u.x, l.u.x);
  unpack2(pa.z, pa.w, h.u.y, l.u.y);
  unpack2(pb.x, pb.y, h.u.z, l.u.z);
  unpack2(pb.z, pb.w, h.u.w, l.u.w);
  hi = h.s; lo = l.s;
}
// 3-term split-bf16 product over 2 k-steps: acc += A*B (~fp32 accuracy)
__device__ __forceinline__ f32x4 mm_split(f32x4 acc, const short8* Ah, const short8* Al,
                                          const short8* Bh, const short8* Bl) {
  acc = __builtin_amdgcn_mfma_f32_16x16x32_bf16(Ah[0], Bh[0], acc, 0, 0, 0);
  acc = __builtin_amdgcn_mfma_f32_16x16x32_bf16(Ah[1], Bh[1], acc, 0, 0, 0);
  acc = __builtin_amdgcn_mfma_f32_16x16x32_bf16(Al[0], Bh[0], acc, 0, 0, 0);
  acc = __builtin_amdgcn_mfma_f32_16x16x32_bf16(Al[1], Bh[1], acc, 0, 0, 0);
  acc = __builtin_amdgcn_mfma_f32_16x16x32_bf16(Ah[0], Bl[0], acc, 0, 0, 0);
  acc = __builtin_amdgcn_mfma_f32_16x16x32_bf16(Ah[1], Bl[1], acc, 0, 0, 0);
  return acc;
}

// ---------- K0: one-time weight packing to split-bf16 u32 in ws -------------
// wpx: 256 rows (xp_w1..w4, 64 rows each) x 64.  wpp: 144 rows (W_M, cb1-rows,
// zw0, zw1) x 64.
__global__ __launch_bounds__(256) void k_prep(
    const float* __restrict__ w1, const float* __restrict__ w2,
    const float* __restrict__ w3, const float* __restrict__ w4,
    const float* __restrict__ cw1, const float* __restrict__ cb1,
    const float* __restrict__ zw0, const float* __restrict__ zw1,
    uint32_t* __restrict__ wpx, uint32_t* __restrict__ wpp)
{
  int e = blockIdx.x * 256 + threadIdx.x;
  if (e < 16384) {
    int o = e >> 6, k = e & 63;
    int lyr = o >> 6, r = o & 63;
    const float* Ws[4] = {w1, w2, w3, w4};
    wpx[e] = packsplit(Ws[lyr][r * 64 + k]);
  } else if (e < 16384 + 9216) {
    int e2 = e - 16384;
    int o = e2 >> 6, k = e2 & 63;
    float wv;
    if (o < 64)       wv = cw1[(((o >> 3) * 64 + k) << 3) + (o & 7)];
    else if (o < 72)  wv = cb1[(o - 64) * 64 + k];
    else if (o < 136) wv = zw0[(o - 72) * 64 + k];
    else              wv = zw1[(o - 136) * 64 + k];
    wpp[e2] = packsplit(wv);
  }
}

// ---------------- K1: x_proj via split-bf16 MFMA + x_rec copy ----------------
// B-frags stream from L1/L2-resident packed weights (wpx); no weight LDS, no
// inter-layer barriers (hbuf rows wave-private; same-wave DS ordering).
// x_old emitted pre-packed split-bf16 u32 (halves write traffic).
__global__ __launch_bounds__(256, 3) void k_xproj(
    const float* __restrict__ x,
    const float* __restrict__ w0, const float* __restrict__ b0,
    const float* __restrict__ b1, const float* __restrict__ b2,
    const float* __restrict__ b3, const float* __restrict__ b4,
    const uint32_t* __restrict__ wpx,
    uint32_t* __restrict__ x_old, float* __restrict__ out)
{
  __shared__ uint32_t hbuf[128 * HSTRIDE];  // activations, packed (hi|lo)
  __shared__ float bs[320];                 // b0..b4

  int tid = threadIdx.x;
  int wave = tid >> 6, lane = tid & 63;
  int quad = lane >> 4, m16 = lane & 15;
  size_t tokBase = (size_t)blockIdx.x * 128;

  {
    size_t e = tokBase * 8 + (size_t)tid * 4;
    *(float4*)(out + e) = *(const float4*)(x + e);
  }
  if (tid < 64) {
    bs[tid]       = b0[tid];
    bs[64 + tid]  = b1[tid];
    bs[128 + tid] = b2[tid];
    bs[192 + tid] = b3[tid];
    bs[256 + tid] = b4[tid];
  }
  __syncthreads();   // bs visible (the only barrier)

  // ---- layer 0: [128x8] @ w0^T(8->64), K padded to 32 ----
  short8 A0h[2], A0l[2];
  #pragma unroll
  for (int mt = 0; mt < 2; ++mt) {
    U4S8 h, l;
    h.u = make_uint4(0, 0, 0, 0); l.u = make_uint4(0, 0, 0, 0);
    if (quad == 0) {
      const float* xp = x + (tokBase + wave * 32 + mt * 16 + m16) * 8;
      float4 xa = *(const float4*)xp;
      float4 xb = *(const float4*)(xp + 4);
      splitpack2(xa.x, xa.y, h.u.x, l.u.x);
      splitpack2(xa.z, xa.w, h.u.y, l.u.y);
      splitpack2(xb.x, xb.y, h.u.z, l.u.z);
      splitpack2(xb.z, xb.w, h.u.w, l.u.w);
    }
    A0h[mt] = h.s; A0l[mt] = l.s;
  }
  {
    f32x4 acc[2][4];
    #pragma unroll
    for (int mt = 0; mt < 2; ++mt)
      #pragma unroll
      for (int nt = 0; nt < 4; ++nt) {
        float bv = bs[nt * 16 + m16];
        acc[mt][nt] = (f32x4){bv, bv, bv, bv};
      }
    #pragma unroll
    for (int nt = 0; nt < 4; ++nt) {
      U4S8 h, l;
      h.u = make_uint4(0, 0, 0, 0); l.u = make_uint4(0, 0, 0, 0);
      if (quad == 0) {
        const float* wp = w0 + (nt * 16 + m16) * 8;
        float4 wa = *(const float4*)wp;
        float4 wb = *(const float4*)(wp + 4);
        splitpack2(wa.x, wa.y, h.u.x, l.u.x);
        splitpack2(wa.z, wa.w, h.u.y, l.u.y);
        splitpack2(wb.x, wb.y, h.u.z, l.u.z);
        splitpack2(wb.z, wb.w, h.u.w, l.u.w);
      }
      #pragma unroll
      for (int mt = 0; mt < 2; ++mt) {
        acc[mt][nt] = __builtin_amdgcn_mfma_f32_16x16x32_bf16(A0h[mt], h.s, acc[mt][nt], 0, 0, 0);
        acc[mt][nt] = __builtin_amdgcn_mfma_f32_16x16x32_bf16(A0l[mt], h.s, acc[mt][nt], 0, 0, 0);
        acc[mt][nt] = __builtin_amdgcn_mfma_f32_16x16x32_bf16(A0h[mt], l.s, acc[mt][nt], 0, 0, 0);
      }
    }
    #pragma unroll
    for (int mt = 0; mt < 2; ++mt)
      #pragma unroll
      for (int nt = 0; nt < 4; ++nt)
        #pragma unroll
        for (int r = 0; r < 4; ++r) {
          float s = siluf(acc[mt][nt][r]);
          hbuf[(wave * 32 + mt * 16 + quad * 4 + r) * HSTRIDE + nt * 16 + m16] = packsplit(s);
        }
  }

  // ---- layers 1..4: B-frags from packed global (L1-resident) ----
  #pragma unroll 1
  for (int lyr = 0; lyr < 4; ++lyr) {
    const uint32_t* wl = wpx + lyr * 4096;
    short8 Ah[4], Al[4];
    #pragma unroll
    for (int mt = 0; mt < 2; ++mt)
      #pragma unroll
      for (int ks = 0; ks < 2; ++ks)
        readfrag(hbuf + (wave * 32 + mt * 16 + m16) * HSTRIDE + ks * 32 + quad * 8,
                 Ah[mt * 2 + ks], Al[mt * 2 + ks]);

    f32x4 acc[2][4];
    #pragma unroll
    for (int mt = 0; mt < 2; ++mt)
      #pragma unroll
      for (int nt = 0; nt < 4; ++nt) {
        float bv = bs[(lyr + 1) * 64 + nt * 16 + m16];
        acc[mt][nt] = (f32x4){bv, bv, bv, bv};
      }
    #pragma unroll
    for (int nt = 0; nt < 4; ++nt) {
      short8 Bh[2], Bl[2];
      readfrag(wl + (nt * 16 + m16) * 64 + quad * 8,      Bh[0], Bl[0]);
      readfrag(wl + (nt * 16 + m16) * 64 + 32 + quad * 8, Bh[1], Bl[1]);
      #pragma unroll
      for (int mt = 0; mt < 2; ++mt)
        acc[mt][nt] = mm_split(acc[mt][nt], &Ah[mt * 2], &Al[mt * 2], Bh, Bl);
    }

    if (lyr < 3) {
      #pragma unroll
      for (int mt = 0; mt < 2; ++mt)
        #pragma unroll
        for (int nt = 0; nt < 4; ++nt)
          #pragma unroll
          for (int r = 0; r < 4; ++r) {
            float s = siluf(acc[mt][nt][r]);
            hbuf[(wave * 32 + mt * 16 + quad * 4 + r) * HSTRIDE + nt * 16 + m16] = packsplit(s);
          }
    } else {
      #pragma unroll
      for (int mt = 0; mt < 2; ++mt)
        #pragma unroll
        for (int nt = 0; nt < 4; ++nt)
          #pragma unroll
          for (int r = 0; r < 4; ++r) {
            size_t t = tokBase + wave * 32 + mt * 16 + quad * 4 + r;
            x_old[t * 64 + nt * 16 + m16] = packsplit(acc[mt][nt][r]);
          }
    }
  }
}

// ------- K2: per-batch dilated depthwise conv + compression + v + z0 --------
// x_old now packed u32 (half the fetch); unpacked to fp32 at staging.
__global__ __launch_bounds__(256) void k_hist(
    const uint32_t* __restrict__ x_old,
    const float* __restrict__ conv_w, const float* __restrict__ conv_b,
    const float* __restrict__ comp_w, const float* __restrict__ comp_b,
    const float* __restrict__ xw0, const float* __restrict__ xb0,
    const float* __restrict__ xw1, const float* __restrict__ xb1,
    float* __restrict__ a0_o, float* __restrict__ v_o, float* __restrict__ z0_o)
{
  __shared__ float xo[LL * NN];
  __shared__ float red[32];
  __shared__ float hbuf[64];
  int b = blockIdx.x, tid = threadIdx.x;
  const uint32_t* src = x_old + (size_t)b * (LL * NN);
  #pragma unroll
  for (int i = 0; i < 6; ++i) {
    int e4 = i * 256 + tid;
    uint4 pw = ((const uint4*)src)[e4];
    *(float4*)(xo + e4 * 4) =
        make_float4(unpackf(pw.x), unpackf(pw.y), unpackf(pw.z), unpackf(pw.w));
  }
  __syncthreads();
  int c = tid & 63;
  float cw0 = conv_w[c * 3], cw1 = conv_w[c * 3 + 1], cw2 = conv_w[c * 3 + 2];
  float cb = conv_b[c];
  float acc[8];
  #pragma unroll
  for (int q = 0; q < 8; ++q) acc[q] = 0.f;
  #pragma unroll 1
  for (int j = 0; j < 24; ++j) {
    int e = j * 256 + tid;
    int t = e >> 6;
    float s = xo[t * 64 + c] * cw0 + cb;
    if (t + 2 < LL) s += xo[(t + 2) * 64 + c] * cw1;
    if (t + 4 < LL) s += xo[(t + 4) * 64 + c] * cw2;
    float hv = siluf(s);
    #pragma unroll
    for (int q = 0; q < 8; ++q) acc[q] += hv * comp_w[q * 6144 + e];
  }
  #pragma unroll
  for (int q = 0; q < 8; ++q) acc[q] = dppadd<0xB1>(acc[q]);
  #pragma unroll
  for (int q = 0; q < 8; ++q) acc[q] = dppadd<0x4E>(acc[q]);
  #pragma unroll
  for (int q = 0; q < 8; ++q) acc[q] = dppadd<0x141>(acc[q]);
  #pragma unroll
  for (int q = 0; q < 8; ++q) acc[q] = dppadd<0x128>(acc[q]);
  #pragma unroll
  for (int q = 0; q < 8; ++q) acc[q] += __shfl_xor(acc[q], 16, 64);
  #pragma unroll
  for (int q = 0; q < 8; ++q) acc[q] += __shfl_xor(acc[q], 32, 64);
  int wave = tid >> 6, lane = tid & 63;
  if (lane < 8) {
    float sel = acc[0];
    #pragma unroll
    for (int q = 1; q < 8; ++q) sel = (lane == q) ? acc[q] : sel;
    red[wave * 8 + lane] = sel;
  }
  __syncthreads();
  if (tid < 8)
    a0_o[b * 8 + tid] = red[tid] + red[8 + tid] + red[16 + tid] + red[24 + tid] + comp_b[tid];
  if (tid < 64) {
    float a2 = xb0[tid];
    #pragma unroll 8
    for (int k = 0; k < 64; ++k) a2 += xw0[tid * 64 + k] * xo[6080 + k];
    hbuf[tid] = siluf(a2);
  }
  __syncthreads();
  float vr = 0.f;
  if (tid < 64) {
    vr = xb1[tid];
    #pragma unroll 8
    for (int k = 0; k < 64; ++k) vr += xw1[tid * 64 + k] * hbuf[k];
  }
  float s2 = wave_sum(vr * vr);
  if (tid < 64) {
    float nrm = sqrtf(s2) + 1e-8f;
    v_o[b * 64 + tid] = vr / nrm;
    z0_o[b * 64 + tid] = xo[6080 + tid];
  }
}

// ------------- K3: 96-step ODE scan (unchanged from R8, 59 us) --------------
__global__ __launch_bounds__(256) void k_scan(
    const float* __restrict__ a0_i, const float* __restrict__ v_i, const float* __restrict__ z0_i,
    const float* __restrict__ nw0, const float* __restrict__ nb0_p,
    const float* __restrict__ nw1, const float* __restrict__ nb1_p,
    const float* __restrict__ lw0, const float* __restrict__ lb0_p,
    const float* __restrict__ lw1, const float* __restrict__ lb1_p,
    const float* __restrict__ spanA, float* __restrict__ atraj, uint32_t* __restrict__ ztraj)
{
  __shared__ float hshm[4 * 72];
  int tid = threadIdx.x;
  int lane = tid & 63;
  int wv = tid >> 6;
  int b = blockIdx.x * 4 + wv;
  float dt = fminf(fmaxf(spanA[0], 1e-8f), 7.0f);
  int i8 = lane & 7;
  int oct = lane >> 3;
  float* hs = hshm + wv * 72;

  float w0r[8], w1L[8], g0r[8], d1r[8];
  #pragma unroll
  for (int i = 0; i < 8; ++i) w0r[i] = nw0[lane * 8 + i];
  #pragma unroll
  for (int j = 0; j < 8; ++j) w1L[j] = nw1[i8 * 64 + oct * 8 + j];
  #pragma unroll
  for (int i = 0; i < 8; ++i) g0r[i] = lw0[i8 * 8 + i];
  #pragma unroll
  for (int i = 0; i < 8; ++i) d1r[i] = lw1[lane * 8 + i];
  float nb0 = nb0_p[lane];
  float nb1o = nb1_p[i8];
  float lb0o = lb0_p[i8];
  float lb1 = lb1_p[lane];
  float v = v_i[b * 64 + lane];
  float z = z0_i[b * 64 + lane];
  float a_own = a0_i[b * 8 + i8];
  float t0 = wave_sum(v * z);
  float w = z - 2.0f * t0 * v;
  float a_s[8];
  #pragma unroll
  for (int i = 0; i < 8; ++i) a_s[i] = rlane(a_own, i);

  float* ab = atraj + (size_t)b * (PP * 8);
  uint32_t* zb = ztraj + (size_t)b * (PP * NN);
  #pragma unroll 1
  for (int p = 0; p < PP; ++p) {
    float h = nb0;
    #pragma unroll
    for (int i = 0; i < 8; ++i) h += w0r[i] * a_s[i];
    h = siluf(h);
    hs[lane] = h;
    float4 h0 = *(const float4*)(hs + oct * 8);
    float4 h1 = *(const float4*)(hs + oct * 8 + 4);
    float psum = w1L[0] * h0.x + w1L[1] * h0.y + w1L[2] * h0.z + w1L[3] * h0.w
               + w1L[4] * h1.x + w1L[5] * h1.y + w1L[6] * h1.z + w1L[7] * h1.w;
    psum += __shfl_xor(psum, 8, 64);
    psum += __shfl_xor(psum, 16, 64);
    psum += __shfl_xor(psum, 32, 64);
    float da_own = tanhf_fast(psum + nb1o);
    float ga = lb0o;
    #pragma unroll
    for (int i = 0; i < 8; ++i) ga += g0r[i] * a_s[i];
    float g_own = siluf(ga);
    float d = lb1;
    #pragma unroll
    for (int j = 0; j < 8; ++j) d += d1r[j] * rlane(g_own, j);
    a_own += dt * da_own;
    #pragma unroll
    for (int i = 0; i < 8; ++i) a_s[i] = rlane(a_own, i);
    w *= (1.0f + dt * d);
    float t1 = wave_sum(v * w);
    float zv = w - 2.0f * t1 * v;
    if (lane < 8) ab[p * 8 + lane] = a_own;
    zb[p * 64 + lane] = packsplit(zv);
  }
}

// --------- K4: post nets via split-bf16 MFMA, weights from packed global ----
// No weight LDS (wpp is L1/L2-resident, identical across blocks); LDS is just
// ebuf + resbuf -> 4 blocks/CU. One barrier (resbuf cross-wave combine).
__global__ __launch_bounds__(256, 4) void k_post(
    const float* __restrict__ atraj, const uint32_t* __restrict__ ztraj,
    const uint32_t* __restrict__ wpp,
    const float* __restrict__ cw0, const float* __restrict__ cb0,
    const float* __restrict__ zb0, const float* __restrict__ zb1,
    float* __restrict__ out)
{
  __shared__ uint32_t ebuf[64 * HSTRIDE];   // 17408 B
  __shared__ float    resbuf[64 * RSTR];    // 20736 B: M[64], ybias[8], add[8]
  __shared__ float    cw0s[64];
  __shared__ float    cb0s[8];
  __shared__ float    zb0s[64];
  __shared__ float    zb1s[8];

  int tid = threadIdx.x;
  int wave = tid >> 6, lane = tid & 63;
  int quad = lane >> 4, m16 = lane & 15;
  size_t tokBase = (size_t)blockIdx.x * 64;

  if (tid < 64) cw0s[tid] = cw0[tid];
  if (tid < 8)  cb0s[tid] = cb0[tid];
  if (tid < 64) zb0s[tid] = zb0[tid];
  if (tid < 8)  zb1s[tid] = zb1[tid];

  // ---- A-frags (Z) straight from global packed ztraj ----
  const uint32_t* zp = ztraj + (tokBase + wave * 16 + m16) * 64;
  short8 Ah[2], Al[2];
  readfrag(zp + quad * 8,      Ah[0], Al[0]);
  readfrag(zp + 32 + quad * 8, Ah[1], Al[1]);

  // ---- pass 1: M (0..63) + ybias (64..71) ----
  #pragma unroll
  for (int nt = 0; nt < 5; ++nt) {
    short8 Bh[2], Bl[2];
    readfrag(wpp + (nt * 16 + m16) * 64 + quad * 8,      Bh[0], Bl[0]);
    readfrag(wpp + (nt * 16 + m16) * 64 + 32 + quad * 8, Bh[1], Bl[1]);
    f32x4 acc = (f32x4){0.f, 0.f, 0.f, 0.f};
    acc = mm_split(acc, Ah, Al, Bh, Bl);
    int o = nt * 16 + m16;
    if (o < 72) {
      #pragma unroll
      for (int r = 0; r < 4; ++r)
        resbuf[(wave * 16 + quad * 4 + r) * RSTR + o] = acc[r];
    }
  }

  // ---- pass 2: E = silu(Z @ zw0^T + zb0) -> wave-private ebuf ----
  #pragma unroll
  for (int nt = 0; nt < 4; ++nt) {
    short8 Bh[2], Bl[2];
    readfrag(wpp + (72 + nt * 16 + m16) * 64 + quad * 8,      Bh[0], Bl[0]);
    readfrag(wpp + (72 + nt * 16 + m16) * 64 + 32 + quad * 8, Bh[1], Bl[1]);
    f32x4 acc = (f32x4){0.f, 0.f, 0.f, 0.f};
    acc = mm_split(acc, Ah, Al, Bh, Bl);
    int m = nt * 16 + m16;
    float zbv = zb0s[m];
    #pragma unroll
    for (int r = 0; r < 4; ++r) {
      float e = siluf(acc[r] + zbv);
      ebuf[(wave * 16 + quad * 4 + r) * HSTRIDE + m] = packsplit(e);
    }
  }

  // ---- pass 3: add = E @ zw1^T + zb1 ----
  {
    short8 Eh[2], El[2];
    readfrag(ebuf + (wave * 16 + m16) * HSTRIDE + quad * 8,      Eh[0], El[0]);
    readfrag(ebuf + (wave * 16 + m16) * HSTRIDE + 32 + quad * 8, Eh[1], El[1]);
    short8 Bh[2], Bl[2];
    int brow = 136 + (m16 & 7);
    readfrag(wpp + brow * 64 + quad * 8,      Bh[0], Bl[0]);
    readfrag(wpp + brow * 64 + 32 + quad * 8, Bh[1], Bl[1]);
    f32x4 acc = (f32x4){0.f, 0.f, 0.f, 0.f};
    acc = mm_split(acc, Eh, El, Bh, Bl);
    if (m16 < 8) {
      float zbv = zb1s[m16];
      #pragma unroll
      for (int r = 0; r < 4; ++r)
        resbuf[(wave * 16 + quad * 4 + r) * RSTR + 72 + m16] = acc[r] + zbv;
    }
  }
  __syncthreads();

  // ---- combine: 256 threads, thread = (token t, channel-pair cg) ----
  {
    int t = tid & 63, cg = tid >> 6;
    size_t idx = tokBase + t;
    const float* ap = atraj + idx * 8;
    float4 a0v = *(const float4*)ap;
    float4 a1v = *(const float4*)(ap + 4);
    float a[8] = {a0v.x, a0v.y, a0v.z, a0v.w, a1v.x, a1v.y, a1v.z, a1v.w};
    float g2[8];
    #pragma unroll
    for (int j = 0; j < 8; ++j) {
      float tt = cb0s[j];
      #pragma unroll
      for (int i = 0; i < 8; ++i) tt += cw0s[j * 8 + i] * a[i];
      g2[j] = siluf(tt);
    }
    const float* rr = resbuf + t * RSTR;
    int c0 = cg * 2;
    float y0 = rr[64 + c0] + rr[72 + c0];
    float y1 = rr[64 + c0 + 1] + rr[72 + c0 + 1];
    #pragma unroll
    for (int j = 0; j < 8; ++j) {
      y0 += rr[c0 * 8 + j] * g2[j];
      y1 += rr[(c0 + 1) * 8 + j] * g2[j];
    }
    float* op = out + (size_t)(BB * LL * 8) + idx * 8 + c0;
    *(float2*)op = make_float2(y0, y1);
  }
}

extern "C" void kernel_launch(void* const* d_in, const int* in_sizes, int n_in,
                              void* d_out, int out_size, void* d_ws, size_t ws_size,
                              hipStream_t stream) {
  const float* x      = (const float*)d_in[0];
  const float* xp_w0  = (const float*)d_in[1];
  const float* xp_b0  = (const float*)d_in[2];
  const float* xp_w1  = (const float*)d_in[3];
  const float* xp_b1  = (const float*)d_in[4];
  const float* xp_w2  = (const float*)d_in[5];
  const float* xp_b2  = (const float*)d_in[6];
  const float* xp_w3  = (const float*)d_in[7];
  const float* xp_b3  = (const float*)d_in[8];
  const float* xp_w4  = (const float*)d_in[9];
  const float* xp_b4  = (const float*)d_in[10];
  const float* xpp_w0 = (const float*)d_in[11];
  const float* xpp_b0 = (const float*)d_in[12];
  const float* xpp_w1 = (const float*)d_in[13];
  const float* xpp_b1 = (const float*)d_in[14];
  const float* conv_w = (const float*)d_in[15];
  const float* conv_b = (const float*)d_in[16];
  const float* span_A = (const float*)d_in[17];
  const float* comp_w = (const float*)d_in[18];
  const float* comp_b = (const float*)d_in[19];
  const float* net_w0 = (const float*)d_in[20];
  const float* net_b0 = (const float*)d_in[21];
  const float* net_w1 = (const float*)d_in[22];
  const float* net_b1 = (const float*)d_in[23];
  const float* lo_w0  = (const float*)d_in[24];
  const float* lo_b0  = (const float*)d_in[25];
  const float* lo_w1  = (const float*)d_in[26];
  const float* lo_b1  = (const float*)d_in[27];
  const float* lc_w0  = (const float*)d_in[28];
  const float* lc_b0  = (const float*)d_in[29];
  const float* lc_w1  = (const float*)d_in[30];
  const float* lc_b1  = (const float*)d_in[31];
  const float* lz_w0  = (const float*)d_in[32];
  const float* lz_b0  = (const float*)d_in[33];
  const float* lz_w1  = (const float*)d_in[34];
  const float* lz_b1  = (const float*)d_in[35];

  float*    ws    = (float*)d_ws;
  uint32_t* x_old = (uint32_t*)ws;         // (B,L,64) packed u32
  uint32_t* ztraj = (uint32_t*)ws;         // (B,P,64) packed u32 — aliases x_old
  float*    atraj = ws + 12582912;         // (B,P,8)
  float*    a0    = ws + 14155776;         // (B,8)
  float*    vv    = a0 + 2048 * 8;         // (B,64)
  float*    z0    = vv + 2048 * 64;        // (B,64)
  uint32_t* wpx   = (uint32_t*)(z0 + 2048 * 64);  // 16384 u32
  uint32_t* wpp   = wpx + 16384;                  // 9216 u32
  float*    out   = (float*)d_out;

  hipLaunchKernelGGL(k_prep, dim3(100), dim3(256), 0, stream,
                     xp_w1, xp_w2, xp_w3, xp_w4, lc_w1, lc_b1, lz_w0, lz_w1, wpx, wpp);
  hipLaunchKernelGGL(k_xproj, dim3(1536), dim3(256), 0, stream,
                     x, xp_w0, xp_b0, xp_b1, xp_b2, xp_b3, xp_b4, wpx, x_old, out);
  hipLaunchKernelGGL(k_hist, dim3(2048), dim3(256), 0, stream,
                     x_old, conv_w, conv_b, comp_w, comp_b,
                     xpp_w0, xpp_b0, xpp_w1, xpp_b1, a0, vv, z0);
  hipLaunchKernelGGL(k_scan, dim3(512), dim3(256), 0, stream,
                     a0, vv, z0, net_w0, net_b0, net_w1, net_b1,
                     lo_w0, lo_b0, lo_w1, lo_b1, span_A, atraj, ztraj);
  hipLaunchKernelGGL(k_post, dim3(3072), dim3(256), 0, stream,
                     atraj, ztraj, wpp, lc_w0, lc_b0, lz_b0, lz_b1, out);
}

// Round 10
// 308.751 us; speedup vs baseline: 1.0972x; 1.0972x over previous
//
#include <hip/hip_runtime.h>
#include <cstdint>
#include <cstddef>

#define BB 2048
#define LL 96
#define PP 96
#define NN 64
#define HSTRIDE 68   // u32 row stride for packed LDS tiles (64 + 4 pad, 16B-aligned)

typedef __attribute__((ext_vector_type(8))) short short8;  // 8 bf16 (4 VGPRs)
typedef __attribute__((ext_vector_type(4))) float f32x4;

union U4S8 { uint4 u; short8 s; };

__device__ __forceinline__ float siluf(float x) {
  return x * __builtin_amdgcn_rcpf(1.0f + __expf(-x));
}
__device__ __forceinline__ float tanhf_fast(float x) {
  return 1.0f - 2.0f * __builtin_amdgcn_rcpf(1.0f + __expf(2.0f * x));
}
__device__ __forceinline__ float rlane(float x, int l) {
  return __int_as_float(__builtin_amdgcn_readlane(__float_as_int(x), l));
}

// ---- DPP cross-lane ops (VALU pipe); HW-verified R7/R8 ----
template <int CTRL>
__device__ __forceinline__ float dppadd(float x) {
  int y = __builtin_amdgcn_update_dpp(0, __float_as_int(x), CTRL, 0xF, 0xF, false);
  return x + __int_as_float(y);
}
template <int CTRL>
__device__ __forceinline__ float dppmov(float x) {
  int y = __builtin_amdgcn_update_dpp(0, __float_as_int(x), CTRL, 0xF, 0xF, false);
  return __int_as_float(y);
}
__device__ __forceinline__ float wave_sum(float x) {
  x = dppadd<0xB1>(x);
  x = dppadd<0x4E>(x);
  x = dppadd<0x141>(x);
  x = dppadd<0x128>(x);
  x += __shfl_xor(x, 16, 64);
  x += __shfl_xor(x, 32, 64);
  return x;
}

// split fp32 -> (bf16 hi | bf16 lo) packed in one u32 (hi in top 16).
__device__ __forceinline__ uint32_t packsplit(float f) {
  uint32_t b = __float_as_uint(f);
  uint32_t h = b & 0xFFFF0000u;
  float r = f - __uint_as_float(h);
  return h | (__float_as_uint(r) >> 16);
}
__device__ __forceinline__ void splitpack2(float f0, float f1, uint32_t& dhi, uint32_t& dlo) {
  uint32_t b0 = __float_as_uint(f0), b1 = __float_as_uint(f1);
  uint32_t h0 = b0 & 0xFFFF0000u, h1 = b1 & 0xFFFF0000u;
  float r0 = f0 - __uint_as_float(h0), r1 = f1 - __uint_as_float(h1);
  dhi = (h0 >> 16) | h1;
  dlo = (__float_as_uint(r0) >> 16) | (__float_as_uint(r1) & 0xFFFF0000u);
}
__device__ __forceinline__ void unpack2(uint32_t p0, uint32_t p1, uint32_t& dhi, uint32_t& dlo) {
  dhi = (p0 >> 16) | (p1 & 0xFFFF0000u);
  dlo = (p0 & 0xFFFFu) | (p1 << 16);
}
__device__ __forceinline__ void readfrag(const uint32_t* p, short8& hi, short8& lo) {
  uint4 pa = *(const uint4*)p;
  uint4 pb = *(const uint4*)(p + 4);
  U4S8 h, l;
  unpack2(pa.x, pa.y, h.u.x, l.u.x);
  unpack2(pa.z, pa.w, h.u.y, l.u.y);
  unpack2(pb.x, pb.y, h.u.z, l.u.z);
  unpack2(pb.z, pb.w, h.u.w, l.u.w);
  hi = h.s; lo = l.s;
}
// 3-term split-bf16 product over 2 k-steps: acc += A*B (~fp32 accuracy)
__device__ __forceinline__ f32x4 mm_split(f32x4 acc, const short8* Ah, const short8* Al,
                                          const short8* Bh, const short8* Bl) {
  acc = __builtin_amdgcn_mfma_f32_16x16x32_bf16(Ah[0], Bh[0], acc, 0, 0, 0);
  acc = __builtin_amdgcn_mfma_f32_16x16x32_bf16(Ah[1], Bh[1], acc, 0, 0, 0);
  acc = __builtin_amdgcn_mfma_f32_16x16x32_bf16(Al[0], Bh[0], acc, 0, 0, 0);
  acc = __builtin_amdgcn_mfma_f32_16x16x32_bf16(Al[1], Bh[1], acc, 0, 0, 0);
  acc = __builtin_amdgcn_mfma_f32_16x16x32_bf16(Ah[0], Bl[0], acc, 0, 0, 0);
  acc = __builtin_amdgcn_mfma_f32_16x16x32_bf16(Ah[1], Bl[1], acc, 0, 0, 0);
  return acc;
}

// ---------------- K1: x_proj (R8 version: LDS dbuf weights) ------------------
__global__ __launch_bounds__(256, 2) void k_xproj(
    const float* __restrict__ x,
    const float* __restrict__ w0, const float* __restrict__ b0,
    const float* __restrict__ w1, const float* __restrict__ b1,
    const float* __restrict__ w2, const float* __restrict__ b2,
    const float* __restrict__ w3, const float* __restrict__ b3,
    const float* __restrict__ w4, const float* __restrict__ b4,
    float* __restrict__ x_old, float* __restrict__ out)
{
  __shared__ uint32_t hbuf[128 * HSTRIDE];
  __shared__ uint32_t wbufA[64 * HSTRIDE];
  __shared__ uint32_t wbufB[64 * HSTRIDE];
  __shared__ float bs[320];

  int tid = threadIdx.x;
  int wave = tid >> 6, lane = tid & 63;
  int quad = lane >> 4, m16 = lane & 15;
  size_t tokBase = (size_t)blockIdx.x * 128;

  {
    size_t e = tokBase * 8 + (size_t)tid * 4;
    *(float4*)(out + e) = *(const float4*)(x + e);
  }
  if (tid < 64) {
    bs[tid]       = b0[tid];
    bs[64 + tid]  = b1[tid];
    bs[128 + tid] = b2[tid];
    bs[192 + tid] = b3[tid];
    bs[256 + tid] = b4[tid];
  }
  #pragma unroll
  for (int i = 0; i < 4; ++i) {
    int e4 = i * 256 + tid;
    int o = e4 >> 4, k = (e4 & 15) << 2;
    float4 wv = ((const float4*)w1)[e4];
    *(uint4*)(wbufA + o * HSTRIDE + k) =
        make_uint4(packsplit(wv.x), packsplit(wv.y), packsplit(wv.z), packsplit(wv.w));
  }
  __syncthreads();

  short8 A0h[2], A0l[2];
  #pragma unroll
  for (int mt = 0; mt < 2; ++mt) {
    U4S8 h, l;
    h.u = make_uint4(0, 0, 0, 0); l.u = make_uint4(0, 0, 0, 0);
    if (quad == 0) {
      const float* xp = x + (tokBase + wave * 32 + mt * 16 + m16) * 8;
      float4 xa = *(const float4*)xp;
      float4 xb = *(const float4*)(xp + 4);
      splitpack2(xa.x, xa.y, h.u.x, l.u.x);
      splitpack2(xa.z, xa.w, h.u.y, l.u.y);
      splitpack2(xb.x, xb.y, h.u.z, l.u.z);
      splitpack2(xb.z, xb.w, h.u.w, l.u.w);
    }
    A0h[mt] = h.s; A0l[mt] = l.s;
  }
  short8 B0h[4], B0l[4];
  #pragma unroll
  for (int nt = 0; nt < 4; ++nt) {
    U4S8 h, l;
    h.u = make_uint4(0, 0, 0, 0); l.u = make_uint4(0, 0, 0, 0);
    if (quad == 0) {
      const float* wp = w0 + (nt * 16 + m16) * 8;
      float4 wa = *(const float4*)wp;
      float4 wb = *(const float4*)(wp + 4);
      splitpack2(wa.x, wa.y, h.u.x, l.u.x);
      splitpack2(wa.z, wa.w, h.u.y, l.u.y);
      splitpack2(wb.x, wb.y, h.u.z, l.u.z);
      splitpack2(wb.z, wb.w, h.u.w, l.u.w);
    }
    B0h[nt] = h.s; B0l[nt] = l.s;
  }
  {
    f32x4 acc[2][4];
    #pragma unroll
    for (int mt = 0; mt < 2; ++mt)
      #pragma unroll
      for (int nt = 0; nt < 4; ++nt) {
        float bv = bs[nt * 16 + m16];
        acc[mt][nt] = (f32x4){bv, bv, bv, bv};
      }
    #pragma unroll
    for (int mt = 0; mt < 2; ++mt)
      #pragma unroll
      for (int nt = 0; nt < 4; ++nt)
        acc[mt][nt] = __builtin_amdgcn_mfma_f32_16x16x32_bf16(A0h[mt], B0h[nt], acc[mt][nt], 0, 0, 0);
    #pragma unroll
    for (int mt = 0; mt < 2; ++mt)
      #pragma unroll
      for (int nt = 0; nt < 4; ++nt)
        acc[mt][nt] = __builtin_amdgcn_mfma_f32_16x16x32_bf16(A0l[mt], B0h[nt], acc[mt][nt], 0, 0, 0);
    #pragma unroll
    for (int mt = 0; mt < 2; ++mt)
      #pragma unroll
      for (int nt = 0; nt < 4; ++nt)
        acc[mt][nt] = __builtin_amdgcn_mfma_f32_16x16x32_bf16(A0h[mt], B0l[nt], acc[mt][nt], 0, 0, 0);
    #pragma unroll
    for (int mt = 0; mt < 2; ++mt)
      #pragma unroll
      for (int nt = 0; nt < 4; ++nt)
        #pragma unroll
        for (int r = 0; r < 4; ++r) {
          float s = siluf(acc[mt][nt][r]);
          hbuf[(wave * 32 + mt * 16 + quad * 4 + r) * HSTRIDE + nt * 16 + m16] = packsplit(s);
        }
  }

  const float* Ws[4] = {w1, w2, w3, w4};
  uint32_t* cur = wbufA;
  uint32_t* nxt = wbufB;
  #pragma unroll 1
  for (int lyr = 0; lyr < 4; ++lyr) {
    float4 wv[4];
    if (lyr < 3) {
      const float* wn = Ws[lyr + 1];
      #pragma unroll
      for (int i = 0; i < 4; ++i) wv[i] = ((const float4*)wn)[i * 256 + tid];
    }
    short8 Bh[8], Bl[8];
    #pragma unroll
    for (int nt = 0; nt < 4; ++nt)
      #pragma unroll
      for (int ks = 0; ks < 2; ++ks)
        readfrag(cur + (nt * 16 + m16) * HSTRIDE + ks * 32 + quad * 8, Bh[nt * 2 + ks], Bl[nt * 2 + ks]);
    short8 Ah[4], Al[4];
    #pragma unroll
    for (int mt = 0; mt < 2; ++mt)
      #pragma unroll
      for (int ks = 0; ks < 2; ++ks)
        readfrag(hbuf + (wave * 32 + mt * 16 + m16) * HSTRIDE + ks * 32 + quad * 8, Ah[mt * 2 + ks], Al[mt * 2 + ks]);

    f32x4 acc[2][4];
    #pragma unroll
    for (int mt = 0; mt < 2; ++mt)
      #pragma unroll
      for (int nt = 0; nt < 4; ++nt) {
        float bv = bs[(lyr + 1) * 64 + nt * 16 + m16];
        acc[mt][nt] = (f32x4){bv, bv, bv, bv};
      }
    #pragma unroll
    for (int ks = 0; ks < 2; ++ks)
      #pragma unroll
      for (int mt = 0; mt < 2; ++mt)
        #pragma unroll
        for (int nt = 0; nt < 4; ++nt)
          acc[mt][nt] = __builtin_amdgcn_mfma_f32_16x16x32_bf16(Ah[mt * 2 + ks], Bh[nt * 2 + ks], acc[mt][nt], 0, 0, 0);
    #pragma unroll
    for (int ks = 0; ks < 2; ++ks)
      #pragma unroll
      for (int mt = 0; mt < 2; ++mt)
        #pragma unroll
        for (int nt = 0; nt < 4; ++nt)
          acc[mt][nt] = __builtin_amdgcn_mfma_f32_16x16x32_bf16(Al[mt * 2 + ks], Bh[nt * 2 + ks], acc[mt][nt], 0, 0, 0);
    #pragma unroll
    for (int ks = 0; ks < 2; ++ks)
      #pragma unroll
      for (int mt = 0; mt < 2; ++mt)
        #pragma unroll
        for (int nt = 0; nt < 4; ++nt)
          acc[mt][nt] = __builtin_amdgcn_mfma_f32_16x16x32_bf16(Ah[mt * 2 + ks], Bl[nt * 2 + ks], acc[mt][nt], 0, 0, 0);

    if (lyr < 3) {
      #pragma unroll
      for (int i = 0; i < 4; ++i) {
        int e4 = i * 256 + tid;
        int o = e4 >> 4, k = (e4 & 15) << 2;
        *(uint4*)(nxt + o * HSTRIDE + k) =
            make_uint4(packsplit(wv[i].x), packsplit(wv[i].y), packsplit(wv[i].z), packsplit(wv[i].w));
      }
    }

    if (lyr < 3) {
      #pragma unroll
      for (int mt = 0; mt < 2; ++mt)
        #pragma unroll
        for (int nt = 0; nt < 4; ++nt)
          #pragma unroll
          for (int r = 0; r < 4; ++r) {
            float s = siluf(acc[mt][nt][r]);
            hbuf[(wave * 32 + mt * 16 + quad * 4 + r) * HSTRIDE + nt * 16 + m16] = packsplit(s);
          }
    } else {
      #pragma unroll
      for (int mt = 0; mt < 2; ++mt)
        #pragma unroll
        for (int nt = 0; nt < 4; ++nt)
          #pragma unroll
          for (int r = 0; r < 4; ++r) {
            size_t t = tokBase + wave * 32 + mt * 16 + quad * 4 + r;
            x_old[t * 64 + nt * 16 + m16] = acc[mt][nt][r];
          }
    }
    __syncthreads();
    uint32_t* tmp = cur; cur = nxt; nxt = tmp;
  }
}

// ------- K2: per-batch conv + compression + v + z0 (R8 version) -------------
__global__ __launch_bounds__(256) void k_hist(
    const float* __restrict__ x_old,
    const float* __restrict__ conv_w, const float* __restrict__ conv_b,
    const float* __restrict__ comp_w, const float* __restrict__ comp_b,
    const float* __restrict__ xw0, const float* __restrict__ xb0,
    const float* __restrict__ xw1, const float* __restrict__ xb1,
    float* __restrict__ a0_o, float* __restrict__ v_o, float* __restrict__ z0_o)
{
  __shared__ float xo[LL * NN];
  __shared__ float red[32];
  __shared__ float hbuf[64];
  int b = blockIdx.x, tid = threadIdx.x;
  const float* src = x_old + (size_t)b * (LL * NN);
  #pragma unroll
  for (int i = 0; i < 6; ++i) {
    int e = (i * 256 + tid) * 4;
    *(float4*)(xo + e) = *(const float4*)(src + e);
  }
  __syncthreads();
  int c = tid & 63;
  float cw0 = conv_w[c * 3], cw1 = conv_w[c * 3 + 1], cw2 = conv_w[c * 3 + 2];
  float cb = conv_b[c];
  float acc[8];
  #pragma unroll
  for (int q = 0; q < 8; ++q) acc[q] = 0.f;
  #pragma unroll 1
  for (int j = 0; j < 24; ++j) {
    int e = j * 256 + tid;
    int t = e >> 6;
    float s = xo[t * 64 + c] * cw0 + cb;
    if (t + 2 < LL) s += xo[(t + 2) * 64 + c] * cw1;
    if (t + 4 < LL) s += xo[(t + 4) * 64 + c] * cw2;
    float hv = siluf(s);
    #pragma unroll
    for (int q = 0; q < 8; ++q) acc[q] += hv * comp_w[q * 6144 + e];
  }
  #pragma unroll
  for (int q = 0; q < 8; ++q) acc[q] = dppadd<0xB1>(acc[q]);
  #pragma unroll
  for (int q = 0; q < 8; ++q) acc[q] = dppadd<0x4E>(acc[q]);
  #pragma unroll
  for (int q = 0; q < 8; ++q) acc[q] = dppadd<0x141>(acc[q]);
  #pragma unroll
  for (int q = 0; q < 8; ++q) acc[q] = dppadd<0x128>(acc[q]);
  #pragma unroll
  for (int q = 0; q < 8; ++q) acc[q] += __shfl_xor(acc[q], 16, 64);
  #pragma unroll
  for (int q = 0; q < 8; ++q) acc[q] += __shfl_xor(acc[q], 32, 64);
  int wave = tid >> 6, lane = tid & 63;
  if (lane < 8) {
    float sel = acc[0];
    #pragma unroll
    for (int q = 1; q < 8; ++q) sel = (lane == q) ? acc[q] : sel;
    red[wave * 8 + lane] = sel;
  }
  __syncthreads();
  if (tid < 8)
    a0_o[b * 8 + tid] = red[tid] + red[8 + tid] + red[16 + tid] + red[24 + tid] + comp_b[tid];
  if (tid < 64) {
    float a2 = xb0[tid];
    #pragma unroll 8
    for (int k = 0; k < 64; ++k) a2 += xw0[tid * 64 + k] * xo[6080 + k];
    hbuf[tid] = siluf(a2);
  }
  __syncthreads();
  float vr = 0.f;
  if (tid < 64) {
    vr = xb1[tid];
    #pragma unroll 8
    for (int k = 0; k < 64; ++k) vr += xw1[tid * 64 + k] * hbuf[k];
  }
  float s2 = wave_sum(vr * vr);
  if (tid < 64) {
    float nrm = sqrtf(s2) + 1e-8f;
    v_o[b * 64 + tid] = vr / nrm;
    z0_o[b * 64 + tid] = xo[6080 + tid];
  }
}

// ------------- K3: 96-step ODE scan (R8 version, 59 us) ---------------------
__global__ __launch_bounds__(256) void k_scan(
    const float* __restrict__ a0_i, const float* __restrict__ v_i, const float* __restrict__ z0_i,
    const float* __restrict__ nw0, const float* __restrict__ nb0_p,
    const float* __restrict__ nw1, const float* __restrict__ nb1_p,
    const float* __restrict__ lw0, const float* __restrict__ lb0_p,
    const float* __restrict__ lw1, const float* __restrict__ lb1_p,
    const float* __restrict__ spanA, float* __restrict__ atraj, uint32_t* __restrict__ ztraj)
{
  __shared__ float hshm[4 * 72];
  int tid = threadIdx.x;
  int lane = tid & 63;
  int wv = tid >> 6;
  int b = blockIdx.x * 4 + wv;
  float dt = fminf(fmaxf(spanA[0], 1e-8f), 7.0f);
  int i8 = lane & 7;
  int oct = lane >> 3;
  float* hs = hshm + wv * 72;

  float w0r[8], w1L[8], g0r[8], d1r[8];
  #pragma unroll
  for (int i = 0; i < 8; ++i) w0r[i] = nw0[lane * 8 + i];
  #pragma unroll
  for (int j = 0; j < 8; ++j) w1L[j] = nw1[i8 * 64 + oct * 8 + j];
  #pragma unroll
  for (int i = 0; i < 8; ++i) g0r[i] = lw0[i8 * 8 + i];
  #pragma unroll
  for (int i = 0; i < 8; ++i) d1r[i] = lw1[lane * 8 + i];
  float nb0 = nb0_p[lane];
  float nb1o = nb1_p[i8];
  float lb0o = lb0_p[i8];
  float lb1 = lb1_p[lane];
  float v = v_i[b * 64 + lane];
  float z = z0_i[b * 64 + lane];
  float a_own = a0_i[b * 8 + i8];
  float t0 = wave_sum(v * z);
  float w = z - 2.0f * t0 * v;
  float a_s[8];
  #pragma unroll
  for (int i = 0; i < 8; ++i) a_s[i] = rlane(a_own, i);

  float* ab = atraj + (size_t)b * (PP * 8);
  uint32_t* zb = ztraj + (size_t)b * (PP * NN);
  #pragma unroll 1
  for (int p = 0; p < PP; ++p) {
    float h = nb0;
    #pragma unroll
    for (int i = 0; i < 8; ++i) h += w0r[i] * a_s[i];
    h = siluf(h);
    hs[lane] = h;
    float4 h0 = *(const float4*)(hs + oct * 8);
    float4 h1 = *(const float4*)(hs + oct * 8 + 4);
    float psum = w1L[0] * h0.x + w1L[1] * h0.y + w1L[2] * h0.z + w1L[3] * h0.w
               + w1L[4] * h1.x + w1L[5] * h1.y + w1L[6] * h1.z + w1L[7] * h1.w;
    psum += __shfl_xor(psum, 8, 64);
    psum += __shfl_xor(psum, 16, 64);
    psum += __shfl_xor(psum, 32, 64);
    float da_own = tanhf_fast(psum + nb1o);
    float ga = lb0o;
    #pragma unroll
    for (int i = 0; i < 8; ++i) ga += g0r[i] * a_s[i];
    float g_own = siluf(ga);
    float d = lb1;
    #pragma unroll
    for (int j = 0; j < 8; ++j) d += d1r[j] * rlane(g_own, j);
    a_own += dt * da_own;
    #pragma unroll
    for (int i = 0; i < 8; ++i) a_s[i] = rlane(a_own, i);
    w *= (1.0f + dt * d);
    float t1 = wave_sum(v * w);
    float zv = w - 2.0f * t1 * v;
    if (lane < 8) ab[p * 8 + lane] = a_own;
    zb[p * 64 + lane] = packsplit(zv);
  }
}

// --------- K4: post nets, register-resident M + ebuf-aliases-wbuf -----------
// LDS = wbuf only (39.7 KB) -> 4 blocks/CU. Pass-1 results stay in registers
// (C-layout); combine via DPP half-row reduce + ror8 partner pull.
__global__ __launch_bounds__(256, 4) void k_post(
    const float* __restrict__ atraj, const uint32_t* __restrict__ ztraj,
    const float* __restrict__ cw0, const float* __restrict__ cb0,
    const float* __restrict__ cw1, const float* __restrict__ cb1,
    const float* __restrict__ zw0, const float* __restrict__ zb0,
    const float* __restrict__ zw1, const float* __restrict__ zb1,
    float* __restrict__ out)
{
  __shared__ uint32_t wbuf[144 * HSTRIDE];  // 39168 B; rows 0..63 reused as ebuf
  __shared__ float    cw0s[64];
  __shared__ float    cb0s[8];
  __shared__ float    zb0s[64];
  __shared__ float    zb1s[8];

  int tid = threadIdx.x;
  int wave = tid >> 6, lane = tid & 63;
  int quad = lane >> 4, m16 = lane & 15;
  size_t tokBase = (size_t)blockIdx.x * 64;

  // ---- stage all weights once (144 rows x 64) ----
  #pragma unroll
  for (int i = 0; i < 36; ++i) {
    int e = i * 256 + tid;
    int o = e >> 6, k = e & 63;
    float wv;
    if (o < 64)       wv = cw1[(((o >> 3) * 64 + k) << 3) + (o & 7)];
    else if (o < 72)  wv = cb1[(o - 64) * 64 + k];
    else if (o < 136) wv = zw0[(o - 72) * 64 + k];
    else              wv = zw1[(o - 136) * 64 + k];
    wbuf[o * HSTRIDE + k] = packsplit(wv);
  }
  if (tid < 64) cw0s[tid] = cw0[tid];
  if (tid < 8)  cb0s[tid] = cb0[tid];
  if (tid < 64) zb0s[tid] = zb0[tid];
  if (tid < 8)  zb1s[tid] = zb1[tid];
  __syncthreads();

  // ---- A-frags (Z) from global packed ztraj ----
  const uint32_t* zp = ztraj + (tokBase + wave * 16 + m16) * 64;
  short8 Ah[2], Al[2];
  readfrag(zp + quad * 8,      Ah[0], Al[0]);
  readfrag(zp + 32 + quad * 8, Ah[1], Al[1]);

  // ---- pass 1: M (nt 0..3) + ybias (nt 4) -> registers ----
  f32x4 acc1[5];
  #pragma unroll
  for (int nt = 0; nt < 5; ++nt) {
    short8 Bh[2], Bl[2];
    readfrag(wbuf + (nt * 16 + m16) * HSTRIDE + quad * 8,      Bh[0], Bl[0]);
    readfrag(wbuf + (nt * 16 + m16) * HSTRIDE + 32 + quad * 8, Bh[1], Bl[1]);
    f32x4 acc = (f32x4){0.f, 0.f, 0.f, 0.f};
    acc1[nt] = mm_split(acc, Ah, Al, Bh, Bl);
  }
  __syncthreads();  // all pass-1 reads of rows 0..79 done -> rows 0..63 reusable

  // ---- pass 2: E = silu(Z @ zw0^T + zb0) -> ebuf (= wbuf rows 0..63) ----
  uint32_t* ebuf = wbuf;
  #pragma unroll
  for (int nt = 0; nt < 4; ++nt) {
    short8 Bh[2], Bl[2];
    readfrag(wbuf + (72 + nt * 16 + m16) * HSTRIDE + quad * 8,      Bh[0], Bl[0]);
    readfrag(wbuf + (72 + nt * 16 + m16) * HSTRIDE + 32 + quad * 8, Bh[1], Bl[1]);
    f32x4 acc = (f32x4){0.f, 0.f, 0.f, 0.f};
    acc = mm_split(acc, Ah, Al, Bh, Bl);
    int m = nt * 16 + m16;
    float zbv = zb0s[m];
    #pragma unroll
    for (int r = 0; r < 4; ++r) {
      float e = siluf(acc[r] + zbv);
      ebuf[(wave * 16 + quad * 4 + r) * HSTRIDE + m] = packsplit(e);
    }
  }

  // ---- pass 3: add = E @ zw1^T + zb1 (ebuf rows wave-private, in-order) ----
  f32x4 acc3;
  {
    short8 Eh[2], El[2];
    readfrag(ebuf + (wave * 16 + m16) * HSTRIDE + quad * 8,      Eh[0], El[0]);
    readfrag(ebuf + (wave * 16 + m16) * HSTRIDE + 32 + quad * 8, Eh[1], El[1]);
    short8 Bh[2], Bl[2];
    int brow = 136 + (m16 & 7);   // duplicate rows for m16>=8; results unused there
    readfrag(wbuf + brow * HSTRIDE + quad * 8,      Bh[0], Bl[0]);
    readfrag(wbuf + brow * HSTRIDE + 32 + quad * 8, Bh[1], Bl[1]);
    f32x4 acc = (f32x4){0.f, 0.f, 0.f, 0.f};
    acc3 = mm_split(acc, Eh, El, Bh, Bl);
  }

  // ---- in-register combine ----
  // Lane (quad, m16) holds M[t=q*4+r][o=nt*16+m16]; c=nt*2+(m16>>3), j=m16&7.
  // yc[t][c] = sum_j g2[t][j] * M[t][c*8+j]: 8-lane half-row reduce; ror8
  // pulls the other half's c-parity. ybias = acc1[4], add = acc3 (lane c=m16<8).
  int j = m16 & 7;
  float cwj[8];
  #pragma unroll
  for (int i = 0; i < 8; ++i) cwj[i] = cw0s[j * 8 + i];
  float cbj = cb0s[j];
  #pragma unroll
  for (int r = 0; r < 4; ++r) {
    size_t idx = tokBase + wave * 16 + quad * 4 + r;
    const float* ap = atraj + idx * 8;
    float4 a0v = *(const float4*)ap;
    float4 a1v = *(const float4*)(ap + 4);
    float g2v = cbj
      + cwj[0] * a0v.x + cwj[1] * a0v.y + cwj[2] * a0v.z + cwj[3] * a0v.w
      + cwj[4] * a1v.x + cwj[5] * a1v.y + cwj[6] * a1v.z + cwj[7] * a1v.w;
    g2v = siluf(g2v);
    float yc[4], qo[4];
    #pragma unroll
    for (int nt = 0; nt < 4; ++nt) {
      float p = acc1[nt][r] * g2v;
      p = dppadd<0xB1>(p);
      p = dppadd<0x4E>(p);
      p = dppadd<0x141>(p);     // sum over 8-lane half-row
      yc[nt] = p;               // c = nt*2 + (m16>>3)
      qo[nt] = dppmov<0x128>(p);// partner half's value: c = nt*2 + 1-(m16>>3)
    }
    if (m16 < 8) {
      int cc = m16;
      int nt = cc >> 1;
      float ye = (nt == 0) ? yc[0] : (nt == 1) ? yc[1] : (nt == 2) ? yc[2] : yc[3];
      float yo = (nt == 0) ? qo[0] : (nt == 1) ? qo[1] : (nt == 2) ? qo[2] : qo[3];
      float y = (cc & 1) ? yo : ye;
      y += acc1[4][r] + acc3[r] + zb1s[cc];
      out[(size_t)(BB * LL * 8) + idx * 8 + cc] = y;
    }
  }
}

extern "C" void kernel_launch(void* const* d_in, const int* in_sizes, int n_in,
                              void* d_out, int out_size, void* d_ws, size_t ws_size,
                              hipStream_t stream) {
  const float* x      = (const float*)d_in[0];
  const float* xp_w0  = (const float*)d_in[1];
  const float* xp_b0  = (const float*)d_in[2];
  const float* xp_w1  = (const float*)d_in[3];
  const float* xp_b1  = (const float*)d_in[4];
  const float* xp_w2  = (const float*)d_in[5];
  const float* xp_b2  = (const float*)d_in[6];
  const float* xp_w3  = (const float*)d_in[7];
  const float* xp_b3  = (const float*)d_in[8];
  const float* xp_w4  = (const float*)d_in[9];
  const float* xp_b4  = (const float*)d_in[10];
  const float* xpp_w0 = (const float*)d_in[11];
  const float* xpp_b0 = (const float*)d_in[12];
  const float* xpp_w1 = (const float*)d_in[13];
  const float* xpp_b1 = (const float*)d_in[14];
  const float* conv_w = (const float*)d_in[15];
  const float* conv_b = (const float*)d_in[16];
  const float* span_A = (const float*)d_in[17];
  const float* comp_w = (const float*)d_in[18];
  const float* comp_b = (const float*)d_in[19];
  const float* net_w0 = (const float*)d_in[20];
  const float* net_b0 = (const float*)d_in[21];
  const float* net_w1 = (const float*)d_in[22];
  const float* net_b1 = (const float*)d_in[23];
  const float* lo_w0  = (const float*)d_in[24];
  const float* lo_b0  = (const float*)d_in[25];
  const float* lo_w1  = (const float*)d_in[26];
  const float* lo_b1  = (const float*)d_in[27];
  const float* lc_w0  = (const float*)d_in[28];
  const float* lc_b0  = (const float*)d_in[29];
  const float* lc_w1  = (const float*)d_in[30];
  const float* lc_b1  = (const float*)d_in[31];
  const float* lz_w0  = (const float*)d_in[32];
  const float* lz_b0  = (const float*)d_in[33];
  const float* lz_w1  = (const float*)d_in[34];
  const float* lz_b1  = (const float*)d_in[35];

  float*    ws    = (float*)d_ws;
  float*    x_old = ws;                    // (B,L,64) fp32
  uint32_t* ztraj = (uint32_t*)ws;         // (B,P,64) packed u32 — aliases x_old
  float*    atraj = ws + 12582912;         // (B,P,8)
  float*    a0    = ws + 14155776;         // (B,8)
  float*    vv    = a0 + 2048 * 8;         // (B,64)
  float*    z0    = vv + 2048 * 64;        // (B,64)
  float*    out   = (float*)d_out;

  hipLaunchKernelGGL(k_xproj, dim3(1536), dim3(256), 0, stream,
                     x, xp_w0, xp_b0, xp_w1, xp_b1, xp_w2, xp_b2, xp_w3, xp_b3,
                     xp_w4, xp_b4, x_old, out);
  hipLaunchKernelGGL(k_hist, dim3(2048), dim3(256), 0, stream,
                     x_old, conv_w, conv_b, comp_w, comp_b,
                     xpp_w0, xpp_b0, xpp_w1, xpp_b1, a0, vv, z0);
  hipLaunchKernelGGL(k_scan, dim3(512), dim3(256), 0, stream,
                     a0, vv, z0, net_w0, net_b0, net_w1, net_b1,
                     lo_w0, lo_b0, lo_w1, lo_b1, span_A, atraj, ztraj);
  hipLaunchKernelGGL(k_post, dim3(3072), dim3(256), 0, stream,
                     atraj, ztraj, lc_w0, lc_b0, lc_w1, lc_b1,
                     lz_w0, lz_b0, lz_w1, lz_b1, out);
}